// Round 18
// baseline (269.000 us; speedup 1.0000x reference)
//
#include <hip/hip_runtime.h>

typedef __bf16 bf16;
typedef __attribute__((ext_vector_type(4))) __bf16 bf16x4;
typedef __attribute__((ext_vector_type(8))) __bf16 bf16x8;
typedef __attribute__((ext_vector_type(4))) float f32x4;
typedef __attribute__((ext_vector_type(4))) _Float16 f16x4;

#define B_   2
#define L_   1024
#define DM_  512
#define H_   8
#define D_   64
#define PD_  64
#define NEG_VAL -10000.0f

static __device__ __forceinline__ f32x4 mfma_bf16(bf16x8 a, bf16x8 b, f32x4 c) {
  return __builtin_amdgcn_mfma_f32_16x16x32_bf16(a, b, c, 0, 0, 0);
}

// ---------------- fused front: interleaved bias (even bids) + prep (odd bids) ----------------
// bias: z @ Wpb -> TILED bias fp16 [b][h][it][jc] 2KB tiles in attn fragment order, mask folded.
// prep: W transposes (1024) + x->bf16 (1024).
__global__ __launch_bounds__(256) void prep_bias(
    const float* __restrict__ z, const float* __restrict__ Wpb, const int* __restrict__ mask,
    const float* __restrict__ x, const float* __restrict__ Wq, const float* __restrict__ Wk,
    const float* __restrict__ Wv, const float* __restrict__ Wo,
    _Float16* __restrict__ biasbuf, bf16* __restrict__ xb, bf16* __restrict__ Wt,
    bf16* __restrict__ Wto) {
  __shared__ char smem[18944];
  int bid0 = blockIdx.x, tid = threadIdx.x;
  if ((bid0 & 1) == 0) {
    int bid = bid0 >> 1;                                 // bias index 0..2047
    _Float16 (*outt)[1032] = (_Float16(*)[1032])smem;    // 16512 B
    float* wpb_lds = (float*)(smem + 16512);             // 2048 B
    int w = tid >> 6, lane = tid & 63;
    int lr = lane & 15, lg = lane >> 4;
    int jc = bid & 15, it = (bid >> 4) & 63, b = bid >> 10;
    if (tid < 128) {
      f32x4 v = reinterpret_cast<const f32x4*>(Wpb)[tid];
      *reinterpret_cast<f32x4*>(wpb_lds + tid * 4) = v;
    }
    __syncthreads();
    bf16x8 wb0, wb1;
#pragma unroll
    for (int e = 0; e < 8; ++e) {
      wb0[e] = (lr < 8) ? (bf16)wpb_lds[(lg * 8 + e) * 8 + lr] : (bf16)0.0f;
      wb1[e] = (lr < 8) ? (bf16)wpb_lds[(lg * 8 + 32 + e) * 8 + lr] : (bf16)0.0f;
    }
#pragma unroll
    for (int ii = 0; ii < 4; ++ii) {
      int il = w * 4 + ii;                     // i-local 0..15
      int i = it * 16 + il;
#pragma unroll
      for (int js = 0; js < 4; ++js) {
        const float* zr = z + ((long)(b * L_ + i) * L_ + jc * 64 + js * 16 + lr) * 64 + lg * 8;
        f32x4 z0 = __builtin_nontemporal_load(reinterpret_cast<const f32x4*>(zr));
        f32x4 z1 = __builtin_nontemporal_load(reinterpret_cast<const f32x4*>(zr + 4));
        f32x4 z2 = __builtin_nontemporal_load(reinterpret_cast<const f32x4*>(zr + 32));
        f32x4 z3 = __builtin_nontemporal_load(reinterpret_cast<const f32x4*>(zr + 36));
        bf16x8 a0, a1;
#pragma unroll
        for (int e = 0; e < 4; ++e) {
          a0[e] = (bf16)z0[e]; a0[e + 4] = (bf16)z1[e];
          a1[e] = (bf16)z2[e]; a1[e + 4] = (bf16)z3[e];
        }
        f32x4 c = {0.f, 0.f, 0.f, 0.f};
        c = mfma_bf16(a0, wb0, c);
        c = mfma_bf16(a1, wb1, c);
        if (lr < 8) {                          // h = lr; j = jc*64 + js*16 + lg*4 + r
          int4 mk = *reinterpret_cast<const int4*>(mask + b * L_ + jc * 64 + js * 16 + lg * 4);
          f16x4 hv;
          hv[0] = mk.x ? (_Float16)c[0] : (_Float16)NEG_VAL;
          hv[1] = mk.y ? (_Float16)c[1] : (_Float16)NEG_VAL;
          hv[2] = mk.z ? (_Float16)c[2] : (_Float16)NEG_VAL;
          hv[3] = mk.w ? (_Float16)c[3] : (_Float16)NEG_VAL;
          *reinterpret_cast<f16x4*>(&outt[lr][((js * 4 + lg) * 16 + il) * 4]) = hv;
        }
      }
    }
    __syncthreads();
    {
      int h = tid & 7, part = tid >> 3;        // 8 h x 32 parts of 64B
      _Float16* dst = biasbuf + (((((long)b * H_ + h) * 64 + it) * 16 + jc) << 10) + part * 32;
      const _Float16* srcl = &outt[h][part * 32];
#pragma unroll
      for (int e = 0; e < 8; ++e)
        *reinterpret_cast<f16x4*>(dst + e * 4) = *reinterpret_cast<const f16x4*>(srcl + e * 4);
    }
  } else {
    int pbid = bid0 >> 1;                      // prep index 0..2047
    if (pbid < 1024) {
      float (*td)[33] = (float(*)[33])smem;    // 4224 B
      int r = tid >> 3, c4 = (tid & 7) * 4;
      const float* src;
      bf16* dstbase;
      int n0, k0, srcol;
      if (pbid < 768) {
        int nt2 = pbid >> 4, kt = pbid & 15;
        n0 = nt2 * 32; k0 = kt * 32;
        int sel = n0 >> 9;
        src = sel == 0 ? Wq : (sel == 1 ? Wk : Wv);
        srcol = n0 & 511;
        dstbase = Wt + (long)n0 * 512;
      } else {
        int t2 = pbid - 768;
        int nt2 = t2 >> 4, kt = t2 & 15;
        n0 = nt2 * 32; k0 = kt * 32;
        src = Wo; srcol = n0;
        dstbase = Wto + (long)n0 * 512;
      }
      f32x4 v = *reinterpret_cast<const f32x4*>(src + (long)(k0 + r) * 512 + srcol + c4);
#pragma unroll
      for (int e = 0; e < 4; ++e) td[r][c4 + e] = v[e];
      __syncthreads();
      int nl = tid >> 3, k4 = (tid & 7) * 4;
      bf16x4 o;
#pragma unroll
      for (int e = 0; e < 4; ++e) o[e] = (bf16)td[k4 + e][nl];
      *reinterpret_cast<bf16x4*>(dstbase + (long)nl * 512 + k0 + k4) = o;
    } else {
      int base = (pbid - 1024) * 1024 + tid * 4;
      f32x4 v = *reinterpret_cast<const f32x4*>(x + base);
      bf16x4 o;
#pragma unroll
      for (int e = 0; e < 4; ++e) o[e] = (bf16)v[e];
      *reinterpret_cast<bf16x4*>(xb + base) = o;
    }
  }
}

// ---------------- qkv-v2: 1536 blocks, B-panel LDS-staged. Block = 128M x 16N ----------------
__global__ __launch_bounds__(256) void qkv_gemm(
    const bf16* __restrict__ xb, const bf16* __restrict__ Wt,
    const float* __restrict__ bq, const float* __restrict__ bk, const float* __restrict__ bv,
    bf16* __restrict__ qb, bf16* __restrict__ kb, bf16* __restrict__ vT) {
  __shared__ bf16 bpanel[16 * 520];            // padded rows
  int tid = threadIdx.x, w = tid >> 6, lane = tid & 63;
  int lr = lane & 15, lg = lane >> 4;
  int bid = blockIdx.x;
  int mt = bid / 96, nt = bid - mt * 96;       // 16 x 96
  int col0 = nt * 16;
  {
    const bf16* src = Wt + (long)col0 * 512;
#pragma unroll
    for (int q = 0; q < 4; ++q) {
      int off = q * 2048 + tid * 8;
      int row = off >> 9, col = off & 511;
      *reinterpret_cast<bf16x8*>(&bpanel[row * 520 + col]) =
          *reinterpret_cast<const bf16x8*>(src + off);
    }
  }
  __syncthreads();
  int m0base = mt * 128 + w * 32;
  const bf16* a0p = xb + (long)(m0base + lr) * 512 + lg * 8;
  const bf16* a1p = a0p + 16 * 512;
  f32x4 acc0 = {0.f, 0.f, 0.f, 0.f}, acc1 = acc0;
#pragma unroll
  for (int kk = 0; kk < 512; kk += 32) {
    bf16x8 a0 = *reinterpret_cast<const bf16x8*>(a0p + kk);
    bf16x8 a1 = *reinterpret_cast<const bf16x8*>(a1p + kk);
    bf16x8 b = *reinterpret_cast<const bf16x8*>(&bpanel[lr * 520 + kk + lg * 8]);
    acc0 = mfma_bf16(a0, b, acc0);
    acc1 = mfma_bf16(a1, b, acc1);
  }
  int col = col0 + lr;
  int wsel = col >> 9;
  int ncol = col & 511;
  int h = ncol >> 6, d = ncol & 63;
  const float* bias = wsel == 0 ? bq : (wsel == 1 ? bk : bv);
  float bval = bias[ncol];
#pragma unroll
  for (int mi = 0; mi < 2; ++mi) {
    f32x4 acc = (mi == 0) ? acc0 : acc1;
    int m0 = m0base + mi * 16 + lg * 4;
    int bidx = m0 >> 10, l0 = m0 & 1023;
    if (wsel == 2) {
      bf16x4 pv;
#pragma unroll
      for (int r = 0; r < 4; ++r) pv[r] = (bf16)(acc[r] + bval);
      *reinterpret_cast<bf16x4*>(vT + ((long)(bidx * H_ + h) * D_ + d) * L_ + l0) = pv;
    } else if (wsel == 0) {
#pragma unroll
      for (int r = 0; r < 4; ++r)
        qb[((long)(bidx * H_ + h) * L_ + l0 + r) * D_ + d] = (bf16)((acc[r] + bval) * 0.125f);
    } else {
#pragma unroll
      for (int r = 0; r < 4; ++r)
        kb[((long)(bidx * H_ + h) * L_ + l0 + r) * D_ + d] = (bf16)(acc[r] + bval);
    }
  }
}

// ---------------- attention: swapped-operand, barrier-free j-loop, tiled bias reads ----------------
__global__ __launch_bounds__(256) void attn_kernel(
    const bf16* __restrict__ qb, const bf16* __restrict__ kb, const bf16* __restrict__ vT,
    const _Float16* __restrict__ biasb, const int* __restrict__ mask, bf16* __restrict__ attn_out) {
  __shared__ bf16 p_lds[4][16 * 64];
  __shared__ float o_lds[4][16][68];           // padded: conflict-free merge writes
  __shared__ float m_lds[4][16];
  __shared__ float l_lds[4][16];
  int bid = blockIdx.x;
  int b = bid >> 9, h = (bid >> 6) & 7, it = bid & 63;
  int i0 = it * 16;
  int tid = threadIdx.x, w = tid >> 6, lane = tid & 63, lr = lane & 15, lg = lane >> 4;

  const bf16* qrow = qb + ((long)(b * H_ + h) * L_ + i0 + lr) * D_ + lg * 8;
  bf16x8 qa0 = *reinterpret_cast<const bf16x8*>(qrow);
  bf16x8 qa1 = *reinterpret_cast<const bf16x8*>(qrow + 32);
  const bf16* kbase = kb + (long)(b * H_ + h) * L_ * D_;
  const bf16* vbase = vT + (long)(b * H_ + h) * D_ * L_;
  const _Float16* bias_base = biasb + ((((long)(b * H_ + h) * 64 + it)) << 14);
  bool qok = mask[b * L_ + i0 + lr] != 0;

  float m = -3.0e38f, l = 0.f;
  f32x4 o0 = {0.f,0.f,0.f,0.f}, o1 = o0, o2 = o0, o3 = o0;
  char* pbuf = (char*)&p_lds[w][0];
  int swz = (lr & 7) << 4;

  for (int jt = 0; jt < 4; ++jt) {
    int j0 = w * 256 + jt * 64;
    const _Float16* btile = bias_base + ((w * 4 + jt) << 10);
    f32x4 s0, s1, s2, s3;
#pragma unroll
    for (int tile = 0; tile < 4; ++tile) {
      f16x4 bv = *reinterpret_cast<const f16x4*>(btile + ((tile * 4 + lg) * 16 + lr) * 4);
      f32x4 acc;
#pragma unroll
      for (int r = 0; r < 4; ++r) acc[r] = (float)bv[r];
      const bf16* kr = kbase + (long)(j0 + tile * 16 + lr) * D_ + lg * 8;
      acc = mfma_bf16(*reinterpret_cast<const bf16x8*>(kr), qa0, acc);
      acc = mfma_bf16(*reinterpret_cast<const bf16x8*>(kr + 32), qa1, acc);
      if (tile == 0) s0 = acc; else if (tile == 1) s1 = acc; else if (tile == 2) s2 = acc; else s3 = acc;
    }
    if (!qok) {
#pragma unroll
      for (int r = 0; r < 4; ++r) { s0[r] = NEG_VAL; s1[r] = NEG_VAL; s2[r] = NEG_VAL; s3[r] = NEG_VAL; }
    }
    float mt = s0[0];
#pragma unroll
    for (int r = 0; r < 4; ++r) mt = fmaxf(fmaxf(fmaxf(mt, s0[r]), fmaxf(s1[r], s2[r])), s3[r]);
    mt = fmaxf(mt, __shfl_xor(mt, 16));
    mt = fmaxf(mt, __shfl_xor(mt, 32));
    float mnew = fmaxf(m, mt);
    float alpha = __expf(m - mnew);
    m = mnew;
    f32x4 p0, p1, p2, p3;
    float ps = 0.f;
#pragma unroll
    for (int r = 0; r < 4; ++r) {
      p0[r] = __expf(s0[r] - mnew); p1[r] = __expf(s1[r] - mnew);
      p2[r] = __expf(s2[r] - mnew); p3[r] = __expf(s3[r] - mnew);
      ps += p0[r] + p1[r] + p2[r] + p3[r];
    }
    ps += __shfl_xor(ps, 16);
    ps += __shfl_xor(ps, 32);
    l = l * alpha + ps;
#pragma unroll
    for (int r = 0; r < 4; ++r) { o0[r] *= alpha; o1[r] *= alpha; o2[r] *= alpha; o3[r] *= alpha; }
#pragma unroll
    for (int tile = 0; tile < 4; ++tile) {
      f32x4 pv = (tile == 0) ? p0 : (tile == 1) ? p1 : (tile == 2) ? p2 : p3;
      bf16x4 pb_;
#pragma unroll
      for (int r = 0; r < 4; ++r) pb_[r] = (bf16)pv[r];
      *reinterpret_cast<bf16x4*>(pbuf + ((lr * 128 + tile * 32 + lg * 8) ^ swz)) = pb_;
    }
    bf16x8 pa0 = *reinterpret_cast<const bf16x8*>(pbuf + ((lr * 128 + lg * 16) ^ swz));
    bf16x8 pa1 = *reinterpret_cast<const bf16x8*>(pbuf + ((lr * 128 + 64 + lg * 16) ^ swz));
#pragma unroll
    for (int dtile = 0; dtile < 4; ++dtile) {
      const bf16* vr = vbase + (long)(dtile * 16 + lr) * L_ + j0 + lg * 8;
      f32x4 acc = (dtile == 0) ? o0 : (dtile == 1) ? o1 : (dtile == 2) ? o2 : o3;
      acc = mfma_bf16(*reinterpret_cast<const bf16x8*>(vr), pa0, acc);
      acc = mfma_bf16(*reinterpret_cast<const bf16x8*>(vr + 32), pa1, acc);
      if (dtile == 0) o0 = acc; else if (dtile == 1) o1 = acc; else if (dtile == 2) o2 = acc; else o3 = acc;
    }
  }
#pragma unroll
  for (int dtile = 0; dtile < 4; ++dtile) {
    f32x4 ov = (dtile == 0) ? o0 : (dtile == 1) ? o1 : (dtile == 2) ? o2 : o3;
    *reinterpret_cast<f32x4*>(&o_lds[w][lr][dtile * 16 + lg * 4]) = ov;
  }
  if (lg == 0) { m_lds[w][lr] = m; l_lds[w][lr] = l; }
  __syncthreads();
  {
    int row = tid >> 4, d0 = (tid & 15) * 4;
    float M = fmaxf(fmaxf(m_lds[0][row], m_lds[1][row]), fmaxf(m_lds[2][row], m_lds[3][row]));
    float lt = 0.f;
    float oacc[4] = {0.f, 0.f, 0.f, 0.f};
#pragma unroll
    for (int ww = 0; ww < 4; ++ww) {
      float c = __expf(m_lds[ww][row] - M);
      lt += c * l_lds[ww][row];
#pragma unroll
      for (int e = 0; e < 4; ++e) oacc[e] += c * o_lds[ww][row][d0 + e];
    }
    float inv = 1.0f / lt;
    bf16x4 ov;
#pragma unroll
    for (int e = 0; e < 4; ++e) ov[e] = (bf16)(oacc[e] * inv);
    *reinterpret_cast<bf16x4*>(attn_out + ((long)(b * L_ + i0 + row)) * DM_ + h * D_ + d0) = ov;
  }
}

// ---------------- out: attn_out(2048x512) @ Wto^T -> d_out fp32 + bo ----------------
__global__ __launch_bounds__(256) void out_gemm(
    const bf16* __restrict__ ab, const bf16* __restrict__ Wto,
    const float* __restrict__ bo, float* __restrict__ out) {
  int wid = blockIdx.x * 4 + (threadIdx.x >> 6);
  int lane = threadIdx.x & 63;
  int mt = wid >> 4, nt = wid & 15;    // 64 x 16 tiles of 32x32
  int row0 = mt * 32, col0 = nt * 32;
  int lr = lane & 15, lg = lane >> 4;
  const bf16* a0p = ab + (row0 + lr) * 512 + lg * 8;
  const bf16* a1p = a0p + 16 * 512;
  const bf16* b0p = Wto + (col0 + lr) * 512 + lg * 8;
  const bf16* b1p = b0p + 16 * 512;
  f32x4 acc00 = {0.f,0.f,0.f,0.f}, acc01 = acc00, acc10 = acc00, acc11 = acc00;
#pragma unroll
  for (int kk = 0; kk < 512; kk += 32) {
    bf16x8 a0 = *reinterpret_cast<const bf16x8*>(a0p + kk);
    bf16x8 a1 = *reinterpret_cast<const bf16x8*>(a1p + kk);
    bf16x8 b0 = *reinterpret_cast<const bf16x8*>(b0p + kk);
    bf16x8 b1 = *reinterpret_cast<const bf16x8*>(b1p + kk);
    acc00 = mfma_bf16(a0, b0, acc00);
    acc01 = mfma_bf16(a0, b1, acc01);
    acc10 = mfma_bf16(a1, b0, acc10);
    acc11 = mfma_bf16(a1, b1, acc11);
  }
#pragma unroll
  for (int ni = 0; ni < 2; ++ni) {
    int col = col0 + ni * 16 + lr;
    float bval = bo[col];
#pragma unroll
    for (int mi = 0; mi < 2; ++mi) {
      f32x4 acc = (mi == 0) ? (ni == 0 ? acc00 : acc01) : (ni == 0 ? acc10 : acc11);
      int m0 = row0 + mi * 16 + lg * 4;
#pragma unroll
      for (int r = 0; r < 4; ++r) out[(long)(m0 + r) * 512 + col] = acc[r] + bval;
    }
  }
}

extern "C" void kernel_launch(void* const* d_in, const int* in_sizes, int n_in,
                              void* d_out, int out_size, void* d_ws, size_t ws_size,
                              hipStream_t stream) {
  const float* x    = (const float*)d_in[0];
  const float* z    = (const float*)d_in[1];
  const int*   mask = (const int*)d_in[2];
  const float* Wq   = (const float*)d_in[3];
  const float* bq   = (const float*)d_in[4];
  const float* Wk   = (const float*)d_in[5];
  const float* bk   = (const float*)d_in[6];
  const float* Wv   = (const float*)d_in[7];
  const float* bv   = (const float*)d_in[8];
  const float* Wo   = (const float*)d_in[9];
  const float* bo   = (const float*)d_in[10];
  const float* Wpb  = (const float*)d_in[11];

  char* ws = (char*)d_ws;
  bf16* xb        = (bf16*)(ws + 0);                    // 2 MB
  bf16* Wt        = (bf16*)(ws + 2097152);              // 1.5 MB
  bf16* Wto       = (bf16*)(ws + 3670016);              // 0.5 MB
  bf16* qbuf      = (bf16*)(ws + 4196352);              // 2 MB
  bf16* kbuf      = (bf16*)(ws + 6293504);              // 2 MB
  bf16* vTbuf     = (bf16*)(ws + 8390656);              // 2 MB
  bf16* attn_out  = (bf16*)(ws + 10487808);             // 2 MB
  _Float16* biasb = (_Float16*)(ws + 12584960);         // 33.5 MB (tiled layout)

  prep_bias<<<4096, 256, 0, stream>>>(z, Wpb, mask, x, Wq, Wk, Wv, Wo,
                                      biasb, xb, Wt, Wto);
  qkv_gemm<<<1536, 256, 0, stream>>>(xb, Wt, bq, bk, bv, qbuf, kbuf, vTbuf);
  attn_kernel<<<1024, 256, 0, stream>>>(qbuf, kbuf, vTbuf, biasb, mask, attn_out);
  out_gemm<<<256, 256, 0, stream>>>(attn_out, Wto, bo, (float*)d_out);
}

// Round 19
// 186.986 us; speedup vs baseline: 1.4386x; 1.4386x over previous
//
#include <hip/hip_runtime.h>

typedef __bf16 bf16;
typedef __attribute__((ext_vector_type(4))) __bf16 bf16x4;
typedef __attribute__((ext_vector_type(8))) __bf16 bf16x8;
typedef __attribute__((ext_vector_type(4))) float f32x4;
typedef __attribute__((ext_vector_type(4))) _Float16 f16x4;

#define B_   2
#define L_   1024
#define DM_  512
#define H_   8
#define D_   64
#define PD_  64
#define NEG_VAL -10000.0f

static __device__ __forceinline__ f32x4 mfma_bf16(bf16x8 a, bf16x8 b, f32x4 c) {
  return __builtin_amdgcn_mfma_f32_16x16x32_bf16(a, b, c, 0, 0, 0);
}

// ---------------- fused: bias stream (blocks 0..2047) + prep (blocks 2048..4095) ----------------
// bias: z @ Wpb -> TILED bias fp16 [b][h][it][jc] 2KB tiles in attn fragment order, mask folded.
// prep: W transposes (1024 blocks) + x->bf16 (1024 blocks).
__global__ __launch_bounds__(256) void prep_bias(
    const float* __restrict__ z, const float* __restrict__ Wpb, const int* __restrict__ mask,
    const float* __restrict__ x, const float* __restrict__ Wq, const float* __restrict__ Wk,
    const float* __restrict__ Wv, const float* __restrict__ Wo,
    _Float16* __restrict__ biasbuf, bf16* __restrict__ xb, bf16* __restrict__ Wt,
    bf16* __restrict__ Wto) {
  __shared__ char smem[18944];
  int bid = blockIdx.x, tid = threadIdx.x;
  if (bid < 2048) {
    _Float16 (*outt)[1032] = (_Float16(*)[1032])smem;   // 8 x 1032 fp16 = 16512 B
    float* wpb_lds = (float*)(smem + 16512);             // 512 f32 = 2048 B
    int w = tid >> 6, lane = tid & 63;
    int lr = lane & 15, lg = lane >> 4;
    int jc = bid & 15, it = (bid >> 4) & 63, b = bid >> 10;
    if (tid < 128) {
      f32x4 v = reinterpret_cast<const f32x4*>(Wpb)[tid];
      *reinterpret_cast<f32x4*>(wpb_lds + tid * 4) = v;
    }
    __syncthreads();
    bf16x8 wb0, wb1;
#pragma unroll
    for (int e = 0; e < 8; ++e) {
      wb0[e] = (lr < 8) ? (bf16)wpb_lds[(lg * 8 + e) * 8 + lr] : (bf16)0.0f;
      wb1[e] = (lr < 8) ? (bf16)wpb_lds[(lg * 8 + 32 + e) * 8 + lr] : (bf16)0.0f;
    }
#pragma unroll
    for (int ii = 0; ii < 4; ++ii) {
      int il = w * 4 + ii;                     // i-local 0..15
      int i = it * 16 + il;
#pragma unroll
      for (int js = 0; js < 4; ++js) {
        const float* zr = z + ((long)(b * L_ + i) * L_ + jc * 64 + js * 16 + lr) * 64 + lg * 8;
        f32x4 z0 = *reinterpret_cast<const f32x4*>(zr);
        f32x4 z1 = *reinterpret_cast<const f32x4*>(zr + 4);
        f32x4 z2 = *reinterpret_cast<const f32x4*>(zr + 32);
        f32x4 z3 = *reinterpret_cast<const f32x4*>(zr + 36);
        bf16x8 a0, a1;
#pragma unroll
        for (int e = 0; e < 4; ++e) {
          a0[e] = (bf16)z0[e]; a0[e + 4] = (bf16)z1[e];
          a1[e] = (bf16)z2[e]; a1[e + 4] = (bf16)z3[e];
        }
        f32x4 c = {0.f, 0.f, 0.f, 0.f};
        c = mfma_bf16(a0, wb0, c);
        c = mfma_bf16(a1, wb1, c);
        if (lr < 8) {                          // h = lr; j = jc*64 + js*16 + lg*4 + r
          int4 mk = *reinterpret_cast<const int4*>(mask + b * L_ + jc * 64 + js * 16 + lg * 4);
          f16x4 hv;
          hv[0] = mk.x ? (_Float16)c[0] : (_Float16)NEG_VAL;
          hv[1] = mk.y ? (_Float16)c[1] : (_Float16)NEG_VAL;
          hv[2] = mk.z ? (_Float16)c[2] : (_Float16)NEG_VAL;
          hv[3] = mk.w ? (_Float16)c[3] : (_Float16)NEG_VAL;
          *reinterpret_cast<f16x4*>(&outt[lr][((js * 4 + lg) * 16 + il) * 4]) = hv;
        }
      }
    }
    __syncthreads();
    {
      int h = tid & 7, part = tid >> 3;        // 8 h x 32 parts of 64B
      _Float16* dst = biasbuf + (((((long)b * H_ + h) * 64 + it) * 16 + jc) << 10) + part * 32;
      const _Float16* srcl = &outt[h][part * 32];
#pragma unroll
      for (int e = 0; e < 8; ++e)
        *reinterpret_cast<f16x4*>(dst + e * 4) = *reinterpret_cast<const f16x4*>(srcl + e * 4);
    }
  } else {
    int pbid = bid - 2048;
    if (pbid < 1024) {
      float (*td)[33] = (float(*)[33])smem;    // 32 x 33 f32 = 4224 B
      int r = tid >> 3, c4 = (tid & 7) * 4;
      const float* src;
      bf16* dstbase;
      int n0, k0, srcol;
      if (pbid < 768) {
        int nt2 = pbid >> 4, kt = pbid & 15;
        n0 = nt2 * 32; k0 = kt * 32;
        int sel = n0 >> 9;
        src = sel == 0 ? Wq : (sel == 1 ? Wk : Wv);
        srcol = n0 & 511;
        dstbase = Wt + (long)n0 * 512;
      } else {
        int t2 = pbid - 768;
        int nt2 = t2 >> 4, kt = t2 & 15;
        n0 = nt2 * 32; k0 = kt * 32;
        src = Wo; srcol = n0;
        dstbase = Wto + (long)n0 * 512;
      }
      f32x4 v = *reinterpret_cast<const f32x4*>(src + (long)(k0 + r) * 512 + srcol + c4);
#pragma unroll
      for (int e = 0; e < 4; ++e) td[r][c4 + e] = v[e];
      __syncthreads();
      int nl = tid >> 3, k4 = (tid & 7) * 4;
      bf16x4 o;
#pragma unroll
      for (int e = 0; e < 4; ++e) o[e] = (bf16)td[k4 + e][nl];
      *reinterpret_cast<bf16x4*>(dstbase + (long)nl * 512 + k0 + k4) = o;
    } else {
      int base = (pbid - 1024) * 1024 + tid * 4;
      f32x4 v = *reinterpret_cast<const f32x4*>(x + base);
      bf16x4 o;
#pragma unroll
      for (int e = 0; e < 4; ++e) o[e] = (bf16)v[e];
      *reinterpret_cast<bf16x4*>(xb + base) = o;
    }
  }
}

// ---------------- qkv-v2: 1536 blocks, B-panel LDS-staged. Block = 128M x 16N ----------------
__global__ __launch_bounds__(256) void qkv_gemm(
    const bf16* __restrict__ xb, const bf16* __restrict__ Wt,
    const float* __restrict__ bq, const float* __restrict__ bk, const float* __restrict__ bv,
    bf16* __restrict__ qb, bf16* __restrict__ kb, bf16* __restrict__ vT) {
  __shared__ bf16 bpanel[16 * 520];            // padded rows: 520 elems (1040B)
  int tid = threadIdx.x, w = tid >> 6, lane = tid & 63;
  int lr = lane & 15, lg = lane >> 4;
  int bid = blockIdx.x;
  int mt = bid / 96, nt = bid - mt * 96;       // 16 x 96
  int col0 = nt * 16;
  // stage B-panel: 16 rows x 512 bf16, contiguous 16KB from Wt + col0*512
  {
    const bf16* src = Wt + (long)col0 * 512;
#pragma unroll
    for (int q = 0; q < 4; ++q) {
      int off = q * 2048 + tid * 8;            // elem offset, 8 elems (16B)
      int row = off >> 9, col = off & 511;
      *reinterpret_cast<bf16x8*>(&bpanel[row * 520 + col]) =
          *reinterpret_cast<const bf16x8*>(src + off);
    }
  }
  __syncthreads();
  int m0base = mt * 128 + w * 32;
  const bf16* a0p = xb + (long)(m0base + lr) * 512 + lg * 8;
  const bf16* a1p = a0p + 16 * 512;
  f32x4 acc0 = {0.f, 0.f, 0.f, 0.f}, acc1 = acc0;
#pragma unroll
  for (int kk = 0; kk < 512; kk += 32) {
    bf16x8 a0 = *reinterpret_cast<const bf16x8*>(a0p + kk);
    bf16x8 a1 = *reinterpret_cast<const bf16x8*>(a1p + kk);
    bf16x8 b = *reinterpret_cast<const bf16x8*>(&bpanel[lr * 520 + kk + lg * 8]);
    acc0 = mfma_bf16(a0, b, acc0);
    acc1 = mfma_bf16(a1, b, acc1);
  }
  int col = col0 + lr;
  int wsel = col >> 9;
  int ncol = col & 511;
  int h = ncol >> 6, d = ncol & 63;
  const float* bias = wsel == 0 ? bq : (wsel == 1 ? bk : bv);
  float bval = bias[ncol];
#pragma unroll
  for (int mi = 0; mi < 2; ++mi) {
    f32x4 acc = (mi == 0) ? acc0 : acc1;
    int m0 = m0base + mi * 16 + lg * 4;
    int bidx = m0 >> 10, l0 = m0 & 1023;
    if (wsel == 2) {
      bf16x4 pv;
#pragma unroll
      for (int r = 0; r < 4; ++r) pv[r] = (bf16)(acc[r] + bval);
      *reinterpret_cast<bf16x4*>(vT + ((long)(bidx * H_ + h) * D_ + d) * L_ + l0) = pv;
    } else if (wsel == 0) {
#pragma unroll
      for (int r = 0; r < 4; ++r)
        qb[((long)(bidx * H_ + h) * L_ + l0 + r) * D_ + d] = (bf16)((acc[r] + bval) * 0.125f);
    } else {
#pragma unroll
      for (int r = 0; r < 4; ++r)
        kb[((long)(bidx * H_ + h) * L_ + l0 + r) * D_ + d] = (bf16)(acc[r] + bval);
    }
  }
}

// ---------------- attention: swapped-operand, barrier-free j-loop, tiled bias reads ----------------
__global__ __launch_bounds__(256) void attn_kernel(
    const bf16* __restrict__ qb, const bf16* __restrict__ kb, const bf16* __restrict__ vT,
    const _Float16* __restrict__ biasb, const int* __restrict__ mask, bf16* __restrict__ attn_out) {
  __shared__ bf16 p_lds[4][16 * 64];
  __shared__ float o_lds[4][16][68];           // padded 64->68: conflict-free merge writes
  __shared__ float m_lds[4][16];
  __shared__ float l_lds[4][16];
  int bid = blockIdx.x;
  int b = bid >> 9, h = (bid >> 6) & 7, it = bid & 63;
  int i0 = it * 16;
  int tid = threadIdx.x, w = tid >> 6, lane = tid & 63, lr = lane & 15, lg = lane >> 4;

  const bf16* qrow = qb + ((long)(b * H_ + h) * L_ + i0 + lr) * D_ + lg * 8;
  bf16x8 qa0 = *reinterpret_cast<const bf16x8*>(qrow);
  bf16x8 qa1 = *reinterpret_cast<const bf16x8*>(qrow + 32);
  const bf16* kbase = kb + (long)(b * H_ + h) * L_ * D_;
  const bf16* vbase = vT + (long)(b * H_ + h) * D_ * L_;
  const _Float16* bias_base = biasb + ((((long)(b * H_ + h) * 64 + it)) << 14);
  bool qok = mask[b * L_ + i0 + lr] != 0;

  float m = -3.0e38f, l = 0.f;
  f32x4 o0 = {0.f,0.f,0.f,0.f}, o1 = o0, o2 = o0, o3 = o0;
  char* pbuf = (char*)&p_lds[w][0];
  int swz = (lr & 7) << 4;

  for (int jt = 0; jt < 4; ++jt) {
    int j0 = w * 256 + jt * 64;
    const _Float16* btile = bias_base + ((w * 4 + jt) << 10);
    f32x4 s0, s1, s2, s3;
#pragma unroll
    for (int tile = 0; tile < 4; ++tile) {
      f16x4 bv = *reinterpret_cast<const f16x4*>(btile + ((tile * 4 + lg) * 16 + lr) * 4);
      f32x4 acc;
#pragma unroll
      for (int r = 0; r < 4; ++r) acc[r] = (float)bv[r];
      const bf16* kr = kbase + (long)(j0 + tile * 16 + lr) * D_ + lg * 8;
      acc = mfma_bf16(*reinterpret_cast<const bf16x8*>(kr), qa0, acc);
      acc = mfma_bf16(*reinterpret_cast<const bf16x8*>(kr + 32), qa1, acc);
      if (tile == 0) s0 = acc; else if (tile == 1) s1 = acc; else if (tile == 2) s2 = acc; else s3 = acc;
    }
    if (!qok) {
#pragma unroll
      for (int r = 0; r < 4; ++r) { s0[r] = NEG_VAL; s1[r] = NEG_VAL; s2[r] = NEG_VAL; s3[r] = NEG_VAL; }
    }
    float mt = s0[0];
#pragma unroll
    for (int r = 0; r < 4; ++r) mt = fmaxf(fmaxf(fmaxf(mt, s0[r]), fmaxf(s1[r], s2[r])), s3[r]);
    mt = fmaxf(mt, __shfl_xor(mt, 16));
    mt = fmaxf(mt, __shfl_xor(mt, 32));
    float mnew = fmaxf(m, mt);
    float alpha = __expf(m - mnew);
    m = mnew;
    f32x4 p0, p1, p2, p3;
    float ps = 0.f;
#pragma unroll
    for (int r = 0; r < 4; ++r) {
      p0[r] = __expf(s0[r] - mnew); p1[r] = __expf(s1[r] - mnew);
      p2[r] = __expf(s2[r] - mnew); p3[r] = __expf(s3[r] - mnew);
      ps += p0[r] + p1[r] + p2[r] + p3[r];
    }
    ps += __shfl_xor(ps, 16);
    ps += __shfl_xor(ps, 32);
    l = l * alpha + ps;
#pragma unroll
    for (int r = 0; r < 4; ++r) { o0[r] *= alpha; o1[r] *= alpha; o2[r] *= alpha; o3[r] *= alpha; }
#pragma unroll
    for (int tile = 0; tile < 4; ++tile) {
      f32x4 pv = (tile == 0) ? p0 : (tile == 1) ? p1 : (tile == 2) ? p2 : p3;
      bf16x4 pb_;
#pragma unroll
      for (int r = 0; r < 4; ++r) pb_[r] = (bf16)pv[r];
      *reinterpret_cast<bf16x4*>(pbuf + ((lr * 128 + tile * 32 + lg * 8) ^ swz)) = pb_;
    }
    bf16x8 pa0 = *reinterpret_cast<const bf16x8*>(pbuf + ((lr * 128 + lg * 16) ^ swz));
    bf16x8 pa1 = *reinterpret_cast<const bf16x8*>(pbuf + ((lr * 128 + 64 + lg * 16) ^ swz));
#pragma unroll
    for (int dtile = 0; dtile < 4; ++dtile) {
      const bf16* vr = vbase + (long)(dtile * 16 + lr) * L_ + j0 + lg * 8;
      f32x4 acc = (dtile == 0) ? o0 : (dtile == 1) ? o1 : (dtile == 2) ? o2 : o3;
      acc = mfma_bf16(*reinterpret_cast<const bf16x8*>(vr), pa0, acc);
      acc = mfma_bf16(*reinterpret_cast<const bf16x8*>(vr + 32), pa1, acc);
      if (dtile == 0) o0 = acc; else if (dtile == 1) o1 = acc; else if (dtile == 2) o2 = acc; else o3 = acc;
    }
  }
#pragma unroll
  for (int dtile = 0; dtile < 4; ++dtile) {
    f32x4 ov = (dtile == 0) ? o0 : (dtile == 1) ? o1 : (dtile == 2) ? o2 : o3;
    *reinterpret_cast<f32x4*>(&o_lds[w][lr][dtile * 16 + lg * 4]) = ov;
  }
  if (lg == 0) { m_lds[w][lr] = m; l_lds[w][lr] = l; }
  __syncthreads();
  {
    int row = tid >> 4, d0 = (tid & 15) * 4;
    float M = fmaxf(fmaxf(m_lds[0][row], m_lds[1][row]), fmaxf(m_lds[2][row], m_lds[3][row]));
    float lt = 0.f;
    float oacc[4] = {0.f, 0.f, 0.f, 0.f};
#pragma unroll
    for (int ww = 0; ww < 4; ++ww) {
      float c = __expf(m_lds[ww][row] - M);
      lt += c * l_lds[ww][row];
#pragma unroll
      for (int e = 0; e < 4; ++e) oacc[e] += c * o_lds[ww][row][d0 + e];
    }
    float inv = 1.0f / lt;
    bf16x4 ov;
#pragma unroll
    for (int e = 0; e < 4; ++e) ov[e] = (bf16)(oacc[e] * inv);
    *reinterpret_cast<bf16x4*>(attn_out + ((long)(b * L_ + i0 + row)) * DM_ + h * D_ + d0) = ov;
  }
}

// ---------------- out: attn_out(2048x512) @ Wto^T -> d_out fp32 + bo ----------------
__global__ __launch_bounds__(256) void out_gemm(
    const bf16* __restrict__ ab, const bf16* __restrict__ Wto,
    const float* __restrict__ bo, float* __restrict__ out) {
  int wid = blockIdx.x * 4 + (threadIdx.x >> 6);
  int lane = threadIdx.x & 63;
  int mt = wid >> 4, nt = wid & 15;    // 64 x 16 tiles of 32x32
  int row0 = mt * 32, col0 = nt * 32;
  int lr = lane & 15, lg = lane >> 4;
  const bf16* a0p = ab + (row0 + lr) * 512 + lg * 8;
  const bf16* a1p = a0p + 16 * 512;
  const bf16* b0p = Wto + (col0 + lr) * 512 + lg * 8;
  const bf16* b1p = b0p + 16 * 512;
  f32x4 acc00 = {0.f,0.f,0.f,0.f}, acc01 = acc00, acc10 = acc00, acc11 = acc00;
#pragma unroll
  for (int kk = 0; kk < 512; kk += 32) {
    bf16x8 a0 = *reinterpret_cast<const bf16x8*>(a0p + kk);
    bf16x8 a1 = *reinterpret_cast<const bf16x8*>(a1p + kk);
    bf16x8 b0 = *reinterpret_cast<const bf16x8*>(b0p + kk);
    bf16x8 b1 = *reinterpret_cast<const bf16x8*>(b1p + kk);
    acc00 = mfma_bf16(a0, b0, acc00);
    acc01 = mfma_bf16(a0, b1, acc01);
    acc10 = mfma_bf16(a1, b0, acc10);
    acc11 = mfma_bf16(a1, b1, acc11);
  }
#pragma unroll
  for (int ni = 0; ni < 2; ++ni) {
    int col = col0 + ni * 16 + lr;
    float bval = bo[col];
#pragma unroll
    for (int mi = 0; mi < 2; ++mi) {
      f32x4 acc = (mi == 0) ? (ni == 0 ? acc00 : acc01) : (ni == 0 ? acc10 : acc11);
      int m0 = row0 + mi * 16 + lg * 4;
#pragma unroll
      for (int r = 0; r < 4; ++r) out[(long)(m0 + r) * 512 + col] = acc[r] + bval;
    }
  }
}

extern "C" void kernel_launch(void* const* d_in, const int* in_sizes, int n_in,
                              void* d_out, int out_size, void* d_ws, size_t ws_size,
                              hipStream_t stream) {
  const float* x    = (const float*)d_in[0];
  const float* z    = (const float*)d_in[1];
  const int*   mask = (const int*)d_in[2];
  const float* Wq   = (const float*)d_in[3];
  const float* bq   = (const float*)d_in[4];
  const float* Wk   = (const float*)d_in[5];
  const float* bk   = (const float*)d_in[6];
  const float* Wv   = (const float*)d_in[7];
  const float* bv   = (const float*)d_in[8];
  const float* Wo   = (const float*)d_in[9];
  const float* bo   = (const float*)d_in[10];
  const float* Wpb  = (const float*)d_in[11];

  char* ws = (char*)d_ws;
  bf16* xb        = (bf16*)(ws + 0);                    // 2 MB
  bf16* Wt        = (bf16*)(ws + 2097152);              // 1.5 MB
  bf16* Wto       = (bf16*)(ws + 3670016);              // 0.5 MB
  bf16* qbuf      = (bf16*)(ws + 4196352);              // 2 MB
  bf16* kbuf      = (bf16*)(ws + 6293504);              // 2 MB
  bf16* vTbuf     = (bf16*)(ws + 8390656);              // 2 MB
  bf16* attn_out  = (bf16*)(ws + 10487808);             // 2 MB
  _Float16* biasb = (_Float16*)(ws + 12584960);         // 33.5 MB (tiled layout)

  prep_bias<<<4096, 256, 0, stream>>>(z, Wpb, mask, x, Wq, Wk, Wv, Wo,
                                      biasb, xb, Wt, Wto);
  qkv_gemm<<<1536, 256, 0, stream>>>(xb, Wt, bq, bk, bv, qbuf, kbuf, vTbuf);
  attn_kernel<<<1024, 256, 0, stream>>>(qbuf, kbuf, vTbuf, biasb, mask, attn_out);
  out_gemm<<<256, 256, 0, stream>>>(attn_out, Wto, bo, (float*)d_out);
}

// Round 20
// 175.347 us; speedup vs baseline: 1.5341x; 1.0664x over previous
//
#include <hip/hip_runtime.h>

typedef __bf16 bf16;
typedef __attribute__((ext_vector_type(4))) __bf16 bf16x4;
typedef __attribute__((ext_vector_type(8))) __bf16 bf16x8;
typedef __attribute__((ext_vector_type(4))) float f32x4;
typedef __attribute__((ext_vector_type(4))) _Float16 f16x4;
typedef __attribute__((ext_vector_type(2))) _Float16 f16x2;

#define B_   2
#define L_   1024
#define DM_  512
#define H_   8
#define D_   64
#define PD_  64
#define NEG_VAL -10000.0f

static __device__ __forceinline__ f32x4 mfma_bf16(bf16x8 a, bf16x8 b, f32x4 c) {
  return __builtin_amdgcn_mfma_f32_16x16x32_bf16(a, b, c, 0, 0, 0);
}

// ---------------- fused front: slab-bias [0,32768) + prep [32768,34816) ----------------
// bias (R6/R9-measured 98us geometry): block = 64 consecutive pairs (one i, 64 j) =
// one contiguous 16KB z slab -> swizzled LDS -> MFMA -> coalesced [b][h][i][j] fp16
// writes, key-mask folded. prep: W transposes (1024) + x->bf16 (1024).
__global__ __launch_bounds__(256) void prep_bias(
    const float* __restrict__ z, const float* __restrict__ Wpb, const int* __restrict__ mask,
    const float* __restrict__ x, const float* __restrict__ Wq, const float* __restrict__ Wk,
    const float* __restrict__ Wv, const float* __restrict__ Wo,
    _Float16* __restrict__ biasbuf, bf16* __restrict__ xb, bf16* __restrict__ Wt,
    bf16* __restrict__ Wto) {
  __shared__ char smem[19584];
  int bid = blockIdx.x, tid = threadIdx.x;
  if (bid < 32768) {
    float* zt_raw = (float*)smem;                         // 16384 B, col ^= (row&7)<<5
    _Float16 (*bt)[72] = (_Float16(*)[72])(smem + 16384); // 1152 B
    float* wpb_lds = (float*)(smem + 17536);              // 2048 B
    int w = tid >> 6, lane = tid & 63;
    int lr = lane & 15, lg = lane >> 4;
    if (tid < 128) {
      f32x4 v = reinterpret_cast<const f32x4*>(Wpb)[tid];
      *reinterpret_cast<f32x4*>(wpb_lds + tid * 4) = v;
    }
    char* zb = (char*)zt_raw;
    const char* zsrc = (const char*)(z + (long)bid * 4096);  // 64 pairs * 64 f32 contiguous
#pragma unroll
    for (int q = 0; q < 4; ++q) {
      int lb = q * 4096 + tid * 16;
      int row = lb >> 8, col = lb & 255;
      f32x4 v = *reinterpret_cast<const f32x4*>(zsrc + lb);
      *reinterpret_cast<f32x4*>(zb + row * 256 + (col ^ ((row & 7) << 5))) = v;
    }
    __syncthreads();
    bf16x8 wb0, wb1;
#pragma unroll
    for (int e = 0; e < 8; ++e) {
      wb0[e] = (lr < 8) ? (bf16)wpb_lds[(lg * 8 + e) * 8 + lr] : (bf16)0.0f;
      wb1[e] = (lr < 8) ? (bf16)wpb_lds[(lg * 8 + 32 + e) * 8 + lr] : (bf16)0.0f;
    }
    int row = w * 16 + lr;
    int sw = (row & 7) << 5;
    const char* zr = zb + row * 256;
    f32x4 z0 = *reinterpret_cast<const f32x4*>(zr + ((lg * 32) ^ sw));
    f32x4 z1 = *reinterpret_cast<const f32x4*>(zr + (((lg * 32) ^ sw) + 16));
    f32x4 z2 = *reinterpret_cast<const f32x4*>(zr + ((128 + lg * 32) ^ sw));
    f32x4 z3 = *reinterpret_cast<const f32x4*>(zr + (((128 + lg * 32) ^ sw) + 16));
    bf16x8 a0, a1;
#pragma unroll
    for (int e = 0; e < 4; ++e) { a0[e] = (bf16)z0[e]; a0[e + 4] = (bf16)z1[e]; }
#pragma unroll
    for (int e = 0; e < 4; ++e) { a1[e] = (bf16)z2[e]; a1[e + 4] = (bf16)z3[e]; }
    f32x4 acc = {0.f, 0.f, 0.f, 0.f};
    acc = mfma_bf16(a0, wb0, acc);
    acc = mfma_bf16(a1, wb1, acc);
    __syncthreads();
    if (lr < 8) {                        // h = lr, j-local = w*16 + lg*4 + r
      f16x4 hv;
#pragma unroll
      for (int r = 0; r < 4; ++r) hv[r] = (_Float16)acc[r];
      *reinterpret_cast<f16x4*>(&bt[lr][w * 16 + lg * 4]) = hv;
    }
    __syncthreads();
    {
      int h = tid >> 5, part = tid & 31;
      long pb = (long)bid * 64;
      int b = (int)(pb >> 20), i = ((int)(pb >> 10)) & 1023, j0 = (int)pb & 1023;
      int j = j0 + part * 2;
      f16x2 v = *reinterpret_cast<const f16x2*>(&bt[h][part * 2]);
      if (mask[b * L_ + j] == 0)     v[0] = (_Float16)NEG_VAL;   // fold key_ok
      if (mask[b * L_ + j + 1] == 0) v[1] = (_Float16)NEG_VAL;
      _Float16* dst = biasbuf + ((((long)b * H_ + h) * L_ + i) << 10) + j;
      *reinterpret_cast<f16x2*>(dst) = v;
    }
  } else {
    int pbid = bid - 32768;
    if (pbid < 1024) {
      float (*td)[33] = (float(*)[33])smem;    // 4224 B
      int r = tid >> 3, c4 = (tid & 7) * 4;
      const float* src;
      bf16* dstbase;
      int n0, k0, srcol;
      if (pbid < 768) {
        int nt2 = pbid >> 4, kt = pbid & 15;
        n0 = nt2 * 32; k0 = kt * 32;
        int sel = n0 >> 9;
        src = sel == 0 ? Wq : (sel == 1 ? Wk : Wv);
        srcol = n0 & 511;
        dstbase = Wt + (long)n0 * 512;
      } else {
        int t2 = pbid - 768;
        int nt2 = t2 >> 4, kt = t2 & 15;
        n0 = nt2 * 32; k0 = kt * 32;
        src = Wo; srcol = n0;
        dstbase = Wto + (long)n0 * 512;
      }
      f32x4 v = *reinterpret_cast<const f32x4*>(src + (long)(k0 + r) * 512 + srcol + c4);
#pragma unroll
      for (int e = 0; e < 4; ++e) td[r][c4 + e] = v[e];
      __syncthreads();
      int nl = tid >> 3, k4 = (tid & 7) * 4;
      bf16x4 o;
#pragma unroll
      for (int e = 0; e < 4; ++e) o[e] = (bf16)td[k4 + e][nl];
      *reinterpret_cast<bf16x4*>(dstbase + (long)nl * 512 + k0 + k4) = o;
    } else {
      int base = (pbid - 1024) * 1024 + tid * 4;
      f32x4 v = *reinterpret_cast<const f32x4*>(x + base);
      bf16x4 o;
#pragma unroll
      for (int e = 0; e < 4; ++e) o[e] = (bf16)v[e];
      *reinterpret_cast<bf16x4*>(xb + base) = o;
    }
  }
}

// ---------------- qkv-v2: 1536 blocks, B-panel LDS-staged. Block = 128M x 16N ----------------
__global__ __launch_bounds__(256) void qkv_gemm(
    const bf16* __restrict__ xb, const bf16* __restrict__ Wt,
    const float* __restrict__ bq, const float* __restrict__ bk, const float* __restrict__ bv,
    bf16* __restrict__ qb, bf16* __restrict__ kb, bf16* __restrict__ vT) {
  __shared__ bf16 bpanel[16 * 520];            // padded rows
  int tid = threadIdx.x, w = tid >> 6, lane = tid & 63;
  int lr = lane & 15, lg = lane >> 4;
  int bid = blockIdx.x;
  int mt = bid / 96, nt = bid - mt * 96;       // 16 x 96
  int col0 = nt * 16;
  {
    const bf16* src = Wt + (long)col0 * 512;
#pragma unroll
    for (int q = 0; q < 4; ++q) {
      int off = q * 2048 + tid * 8;
      int row = off >> 9, col = off & 511;
      *reinterpret_cast<bf16x8*>(&bpanel[row * 520 + col]) =
          *reinterpret_cast<const bf16x8*>(src + off);
    }
  }
  __syncthreads();
  int m0base = mt * 128 + w * 32;
  const bf16* a0p = xb + (long)(m0base + lr) * 512 + lg * 8;
  const bf16* a1p = a0p + 16 * 512;
  f32x4 acc0 = {0.f, 0.f, 0.f, 0.f}, acc1 = acc0;
#pragma unroll
  for (int kk = 0; kk < 512; kk += 32) {
    bf16x8 a0 = *reinterpret_cast<const bf16x8*>(a0p + kk);
    bf16x8 a1 = *reinterpret_cast<const bf16x8*>(a1p + kk);
    bf16x8 b = *reinterpret_cast<const bf16x8*>(&bpanel[lr * 520 + kk + lg * 8]);
    acc0 = mfma_bf16(a0, b, acc0);
    acc1 = mfma_bf16(a1, b, acc1);
  }
  int col = col0 + lr;
  int wsel = col >> 9;
  int ncol = col & 511;
  int h = ncol >> 6, d = ncol & 63;
  const float* bias = wsel == 0 ? bq : (wsel == 1 ? bk : bv);
  float bval = bias[ncol];
#pragma unroll
  for (int mi = 0; mi < 2; ++mi) {
    f32x4 acc = (mi == 0) ? acc0 : acc1;
    int m0 = m0base + mi * 16 + lg * 4;
    int bidx = m0 >> 10, l0 = m0 & 1023;
    if (wsel == 2) {
      bf16x4 pv;
#pragma unroll
      for (int r = 0; r < 4; ++r) pv[r] = (bf16)(acc[r] + bval);
      *reinterpret_cast<bf16x4*>(vT + ((long)(bidx * H_ + h) * D_ + d) * L_ + l0) = pv;
    } else if (wsel == 0) {
#pragma unroll
      for (int r = 0; r < 4; ++r)
        qb[((long)(bidx * H_ + h) * L_ + l0 + r) * D_ + d] = (bf16)((acc[r] + bval) * 0.125f);
    } else {
#pragma unroll
      for (int r = 0; r < 4; ++r)
        kb[((long)(bidx * H_ + h) * L_ + l0 + r) * D_ + d] = (bf16)(acc[r] + bval);
    }
  }
}

// ---------------- attention: swapped-operand, barrier-free j-loop, row-addressed bias ----------------
__global__ __launch_bounds__(256) void attn_kernel(
    const bf16* __restrict__ qb, const bf16* __restrict__ kb, const bf16* __restrict__ vT,
    const _Float16* __restrict__ biasb, const int* __restrict__ mask, bf16* __restrict__ attn_out) {
  __shared__ bf16 p_lds[4][16 * 64];
  __shared__ float o_lds[4][16][68];           // padded: conflict-free merge writes
  __shared__ float m_lds[4][16];
  __shared__ float l_lds[4][16];
  int bid = blockIdx.x;
  int b = bid >> 9, h = (bid >> 6) & 7, it = bid & 63;
  int i0 = it * 16;
  int tid = threadIdx.x, w = tid >> 6, lane = tid & 63, lr = lane & 15, lg = lane >> 4;

  const bf16* qrow = qb + ((long)(b * H_ + h) * L_ + i0 + lr) * D_ + lg * 8;
  bf16x8 qa0 = *reinterpret_cast<const bf16x8*>(qrow);
  bf16x8 qa1 = *reinterpret_cast<const bf16x8*>(qrow + 32);
  const bf16* kbase = kb + (long)(b * H_ + h) * L_ * D_;
  const bf16* vbase = vT + (long)(b * H_ + h) * D_ * L_;
  const _Float16* bias_base = biasb + ((long)(b * H_ + h) * L_ + i0) * L_;
  bool qok = mask[b * L_ + i0 + lr] != 0;

  float m = -3.0e38f, l = 0.f;
  f32x4 o0 = {0.f,0.f,0.f,0.f}, o1 = o0, o2 = o0, o3 = o0;
  char* pbuf = (char*)&p_lds[w][0];
  int swz = (lr & 7) << 4;

  for (int jt = 0; jt < 4; ++jt) {
    int j0 = w * 256 + jt * 64;
    f32x4 s0, s1, s2, s3;
#pragma unroll
    for (int tile = 0; tile < 4; ++tile) {
      f16x4 bv = *reinterpret_cast<const f16x4*>(bias_base + (long)lr * L_ + j0 + tile * 16 + lg * 4);
      f32x4 acc;
#pragma unroll
      for (int r = 0; r < 4; ++r) acc[r] = (float)bv[r];
      const bf16* kr = kbase + (long)(j0 + tile * 16 + lr) * D_ + lg * 8;
      acc = mfma_bf16(*reinterpret_cast<const bf16x8*>(kr), qa0, acc);
      acc = mfma_bf16(*reinterpret_cast<const bf16x8*>(kr + 32), qa1, acc);
      if (tile == 0) s0 = acc; else if (tile == 1) s1 = acc; else if (tile == 2) s2 = acc; else s3 = acc;
    }
    if (!qok) {
#pragma unroll
      for (int r = 0; r < 4; ++r) { s0[r] = NEG_VAL; s1[r] = NEG_VAL; s2[r] = NEG_VAL; s3[r] = NEG_VAL; }
    }
    float mt = s0[0];
#pragma unroll
    for (int r = 0; r < 4; ++r) mt = fmaxf(fmaxf(fmaxf(mt, s0[r]), fmaxf(s1[r], s2[r])), s3[r]);
    mt = fmaxf(mt, __shfl_xor(mt, 16));
    mt = fmaxf(mt, __shfl_xor(mt, 32));
    float mnew = fmaxf(m, mt);
    float alpha = __expf(m - mnew);
    m = mnew;
    f32x4 p0, p1, p2, p3;
    float ps = 0.f;
#pragma unroll
    for (int r = 0; r < 4; ++r) {
      p0[r] = __expf(s0[r] - mnew); p1[r] = __expf(s1[r] - mnew);
      p2[r] = __expf(s2[r] - mnew); p3[r] = __expf(s3[r] - mnew);
      ps += p0[r] + p1[r] + p2[r] + p3[r];
    }
    ps += __shfl_xor(ps, 16);
    ps += __shfl_xor(ps, 32);
    l = l * alpha + ps;
#pragma unroll
    for (int r = 0; r < 4; ++r) { o0[r] *= alpha; o1[r] *= alpha; o2[r] *= alpha; o3[r] *= alpha; }
#pragma unroll
    for (int tile = 0; tile < 4; ++tile) {
      f32x4 pv = (tile == 0) ? p0 : (tile == 1) ? p1 : (tile == 2) ? p2 : p3;
      bf16x4 pb_;
#pragma unroll
      for (int r = 0; r < 4; ++r) pb_[r] = (bf16)pv[r];
      *reinterpret_cast<bf16x4*>(pbuf + ((lr * 128 + tile * 32 + lg * 8) ^ swz)) = pb_;
    }
    bf16x8 pa0 = *reinterpret_cast<const bf16x8*>(pbuf + ((lr * 128 + lg * 16) ^ swz));
    bf16x8 pa1 = *reinterpret_cast<const bf16x8*>(pbuf + ((lr * 128 + 64 + lg * 16) ^ swz));
#pragma unroll
    for (int dtile = 0; dtile < 4; ++dtile) {
      const bf16* vr = vbase + (long)(dtile * 16 + lr) * L_ + j0 + lg * 8;
      f32x4 acc = (dtile == 0) ? o0 : (dtile == 1) ? o1 : (dtile == 2) ? o2 : o3;
      acc = mfma_bf16(*reinterpret_cast<const bf16x8*>(vr), pa0, acc);
      acc = mfma_bf16(*reinterpret_cast<const bf16x8*>(vr + 32), pa1, acc);
      if (dtile == 0) o0 = acc; else if (dtile == 1) o1 = acc; else if (dtile == 2) o2 = acc; else o3 = acc;
    }
  }
#pragma unroll
  for (int dtile = 0; dtile < 4; ++dtile) {
    f32x4 ov = (dtile == 0) ? o0 : (dtile == 1) ? o1 : (dtile == 2) ? o2 : o3;
    *reinterpret_cast<f32x4*>(&o_lds[w][lr][dtile * 16 + lg * 4]) = ov;
  }
  if (lg == 0) { m_lds[w][lr] = m; l_lds[w][lr] = l; }
  __syncthreads();
  {
    int row = tid >> 4, d0 = (tid & 15) * 4;
    float M = fmaxf(fmaxf(m_lds[0][row], m_lds[1][row]), fmaxf(m_lds[2][row], m_lds[3][row]));
    float lt = 0.f;
    float oacc[4] = {0.f, 0.f, 0.f, 0.f};
#pragma unroll
    for (int ww = 0; ww < 4; ++ww) {
      float c = __expf(m_lds[ww][row] - M);
      lt += c * l_lds[ww][row];
#pragma unroll
      for (int e = 0; e < 4; ++e) oacc[e] += c * o_lds[ww][row][d0 + e];
    }
    float inv = 1.0f / lt;
    bf16x4 ov;
#pragma unroll
    for (int e = 0; e < 4; ++e) ov[e] = (bf16)(oacc[e] * inv);
    *reinterpret_cast<bf16x4*>(attn_out + ((long)(b * L_ + i0 + row)) * DM_ + h * D_ + d0) = ov;
  }
}

// ---------------- out: attn_out(2048x512) @ Wto^T -> d_out fp32 + bo ----------------
__global__ __launch_bounds__(256) void out_gemm(
    const bf16* __restrict__ ab, const bf16* __restrict__ Wto,
    const float* __restrict__ bo, float* __restrict__ out) {
  int wid = blockIdx.x * 4 + (threadIdx.x >> 6);
  int lane = threadIdx.x & 63;
  int mt = wid >> 4, nt = wid & 15;    // 64 x 16 tiles of 32x32
  int row0 = mt * 32, col0 = nt * 32;
  int lr = lane & 15, lg = lane >> 4;
  const bf16* a0p = ab + (row0 + lr) * 512 + lg * 8;
  const bf16* a1p = a0p + 16 * 512;
  const bf16* b0p = Wto + (col0 + lr) * 512 + lg * 8;
  const bf16* b1p = b0p + 16 * 512;
  f32x4 acc00 = {0.f,0.f,0.f,0.f}, acc01 = acc00, acc10 = acc00, acc11 = acc00;
#pragma unroll
  for (int kk = 0; kk < 512; kk += 32) {
    bf16x8 a0 = *reinterpret_cast<const bf16x8*>(a0p + kk);
    bf16x8 a1 = *reinterpret_cast<const bf16x8*>(a1p + kk);
    bf16x8 b0 = *reinterpret_cast<const bf16x8*>(b0p + kk);
    bf16x8 b1 = *reinterpret_cast<const bf16x8*>(b1p + kk);
    acc00 = mfma_bf16(a0, b0, acc00);
    acc01 = mfma_bf16(a0, b1, acc01);
    acc10 = mfma_bf16(a1, b0, acc10);
    acc11 = mfma_bf16(a1, b1, acc11);
  }
#pragma unroll
  for (int ni = 0; ni < 2; ++ni) {
    int col = col0 + ni * 16 + lr;
    float bval = bo[col];
#pragma unroll
    for (int mi = 0; mi < 2; ++mi) {
      f32x4 acc = (mi == 0) ? (ni == 0 ? acc00 : acc01) : (ni == 0 ? acc10 : acc11);
      int m0 = row0 + mi * 16 + lg * 4;
#pragma unroll
      for (int r = 0; r < 4; ++r) out[(long)(m0 + r) * 512 + col] = acc[r] + bval;
    }
  }
}

extern "C" void kernel_launch(void* const* d_in, const int* in_sizes, int n_in,
                              void* d_out, int out_size, void* d_ws, size_t ws_size,
                              hipStream_t stream) {
  const float* x    = (const float*)d_in[0];
  const float* z    = (const float*)d_in[1];
  const int*   mask = (const int*)d_in[2];
  const float* Wq   = (const float*)d_in[3];
  const float* bq   = (const float*)d_in[4];
  const float* Wk   = (const float*)d_in[5];
  const float* bk   = (const float*)d_in[6];
  const float* Wv   = (const float*)d_in[7];
  const float* bv   = (const float*)d_in[8];
  const float* Wo   = (const float*)d_in[9];
  const float* bo   = (const float*)d_in[10];
  const float* Wpb  = (const float*)d_in[11];

  char* ws = (char*)d_ws;
  bf16* xb        = (bf16*)(ws + 0);                    // 2 MB
  bf16* Wt        = (bf16*)(ws + 2097152);              // 1.5 MB
  bf16* Wto       = (bf16*)(ws + 3670016);              // 0.5 MB
  bf16* qbuf      = (bf16*)(ws + 4196352);              // 2 MB
  bf16* kbuf      = (bf16*)(ws + 6293504);              // 2 MB
  bf16* vTbuf     = (bf16*)(ws + 8390656);              // 2 MB
  bf16* attn_out  = (bf16*)(ws + 10487808);             // 2 MB
  _Float16* biasb = (_Float16*)(ws + 12584960);         // 33.5 MB ([b][h][i][j])

  prep_bias<<<34816, 256, 0, stream>>>(z, Wpb, mask, x, Wq, Wk, Wv, Wo,
                                       biasb, xb, Wt, Wto);
  qkv_gemm<<<1536, 256, 0, stream>>>(xb, Wt, bq, bk, bv, qbuf, kbuf, vTbuf);
  attn_kernel<<<1024, 256, 0, stream>>>(qbuf, kbuf, vTbuf, biasb, mask, attn_out);
  out_gemm<<<256, 256, 0, stream>>>(attn_out, Wto, bo, (float*)d_out);
}